// Round 1
// baseline (355.371 us; speedup 1.0000x reference)
//
#include <hip/hip_runtime.h>

#define NN 8192
#define DT_C 1e-3f
#define TAU_C 1e-2f

// Kernel 1: r = tanh(y), 8192 elements.
__global__ void rnn_tanh_kernel(const float* __restrict__ y, float* __restrict__ r) {
    int i = blockIdx.x * blockDim.x + threadIdx.x;
    if (i < NN) r[i] = tanhf(y[i]);
}

// Kernel 2: GEMV + Euler update. One wave per row; r staged in LDS.
__global__ __launch_bounds__(256, 4)
void rnn_gemv_kernel(const float* __restrict__ x, const float* __restrict__ y,
                     const float* __restrict__ W, const float* __restrict__ r,
                     float* __restrict__ out) {
    __shared__ float4 s_r[NN / 4];  // 32 KiB

    const int tid = threadIdx.x;

    // Cooperative stage of r into LDS: 2048 float4, 256 threads -> 8 each.
    const float4* __restrict__ r4 = (const float4*)r;
#pragma unroll
    for (int j = 0; j < NN / 4 / 256; ++j)
        s_r[tid + j * 256] = r4[tid + j * 256];
    __syncthreads();

    const int wave = tid >> 6;
    const int lane = tid & 63;
    const int row  = blockIdx.x * 4 + wave;

    const float4* __restrict__ wrow = (const float4*)(W + (size_t)row * NN);

    float4 acc = make_float4(0.f, 0.f, 0.f, 0.f);
#pragma unroll
    for (int k = 0; k < NN / 4 / 64; ++k) {  // 32 iterations
        const float4 w  = wrow[k * 64 + lane];  // coalesced: 64 lanes x 16B contiguous
        const float4 rv = s_r[k * 64 + lane];
        acc.x = fmaf(w.x, rv.x, acc.x);
        acc.y = fmaf(w.y, rv.y, acc.y);
        acc.z = fmaf(w.z, rv.z, acc.z);
        acc.w = fmaf(w.w, rv.w, acc.w);
    }

    float sum = (acc.x + acc.y) + (acc.z + acc.w);
#pragma unroll
    for (int off = 32; off >= 1; off >>= 1)
        sum += __shfl_down(sum, off, 64);

    if (lane == 0) {
        const float yv = y[row];
        const float xv = x[row];
        const float dy = (-yv + sum + xv) / TAU_C;  // same op order as reference
        out[row] = yv + DT_C * dy;
    }
}

extern "C" void kernel_launch(void* const* d_in, const int* in_sizes, int n_in,
                              void* d_out, int out_size, void* d_ws, size_t ws_size,
                              hipStream_t stream) {
    const float* x = (const float*)d_in[0];
    const float* y = (const float*)d_in[1];
    const float* W = (const float*)d_in[2];
    float* out = (float*)d_out;
    float* r   = (float*)d_ws;  // 8192 floats = 32 KiB scratch

    rnn_tanh_kernel<<<NN / 256, 256, 0, stream>>>(y, r);
    rnn_gemv_kernel<<<NN / 4, 256, 0, stream>>>(x, y, W, r, out);
}